// Round 4
// baseline (739.228 us; speedup 1.0000x reference)
//
#include <hip/hip_runtime.h>

// ct_layer: 5x conv3x3(+BN) + corner pools. Round 4: shared-weight blocks.
//   - Block = 64co x 256n (16x16 spatial). All 4 waves share one 64-co
//     weight set -> A tiles (36KB/ci-block) are L1-resident instead of
//     thrashing through L2.
//   - B: 18x18 halo staged per 32-ci block into LDS (global_load_lds w=16,
//     double buffered, 48KB).
//   - p12 fused as one 512-co conv (co_blk 0..7 -> {p1,p2} x 4 co-quarters).
//   - lin = co_blk*288 + spatial keeps co-blocks of one spatial tile on one
//     XCD (288 % 8 == 0) for B L2 reuse.

typedef _Float16 f16x8 __attribute__((ext_vector_type(8)));
typedef _Float16 f16x4v __attribute__((ext_vector_type(4)));
typedef float f32x4 __attribute__((ext_vector_type(4)));

#define HP 98
#define WP 98
#define KTOT 2304
#define WSET (256*KTOT)                // 589824 elems per weight set
#define XPAD_E ((size_t)8*HP*WP*256)
#define PBUF_E ((size_t)73728*256)
#define UV_E (8*96*256)

#define BUF_B 24576            // one staged ci-slice: 384 pos * 64B (324 valid)
#define SMEM_B 49152           // 2*BUF_B; epilogue lt needs 256*68*2=34816

struct TileCtx {
  unsigned goff[6];            // elem offsets for this thread's 6 stage loads
  unsigned lds_stage;          // byte offset of this thread's t=0 LDS dest
  unsigned aoff;               // lane offset inside a 16co x 32k weight tile
  int hl, wl, quad;
  int co_wg;                   // co base for bias/output (within 256)
  int b, h0, w0;
};

__device__ __forceinline__ TileCtx make_ctx(int spatial, int co_wg)
{
  TileCtx c;
  c.co_wg = co_wg;
  c.b = spatial / 36;
  const int tt = spatial - c.b * 36;
  const int ht = tt / 6, wt = tt - ht * 6;
  c.h0 = ht * 16; c.w0 = wt * 16;
  const int tid = threadIdx.x, lane = tid & 63, wv = tid >> 6;
  c.quad = lane >> 4; c.wl = lane & 15;
  c.hl = wv * 4;
  c.aoff = (unsigned)(c.wl * 32 + c.quad * 8);
  const unsigned base_hw = (unsigned)(c.b * HP + c.h0) * WP + c.w0;
#pragma unroll
  for (int t = 0; t < 6; ++t) {
    int pos = (wv * 6 + t) * 16 + (lane >> 2);   // 0..383; 324..383 dummy
    if (pos > 323) pos = 323;
    const int wh = pos / 18, ww = pos - wh * 18;
    c.goff[t] = (base_hw + (unsigned)(wh * WP + ww)) * 256u + (lane & 3) * 8u;
  }
  c.lds_stage = (unsigned)(wv * 6) * 1024u + (unsigned)lane * 16u;
  return c;
}

__device__ __forceinline__ void stage_cb(const _Float16* __restrict__ src,
                                         char* sbuf, const TileCtx& c,
                                         int buf, int cb)
{
  char* l0 = sbuf + buf * BUF_B + c.lds_stage;
#pragma unroll
  for (int t = 0; t < 6; ++t) {
    const _Float16* g = src + c.goff[t] + cb * 32;
    __builtin_amdgcn_global_load_lds(
        (const __attribute__((address_space(1))) void*)g,
        (__attribute__((address_space(3))) void*)(l0 + t * 1024), 16, 0, 0);
  }
}

// One full conv accumulation (K = 9 taps x 256 ci) into acc[4][4].
// wkb already points at this block's 64-co slice of the tiled weight set:
//   tile idx = (cb*9+tap)*8192 + cog*512 + m*32 + kk   (cog 0..3 local)
__device__ __forceinline__ void conv_accum(const _Float16* __restrict__ src,
                                           const _Float16* __restrict__ wkb,
                                           char* sbuf, const TileCtx& c,
                                           f32x4 acc[4][4])
{
  const _Float16* A0 = wkb + c.aoff;
  const int rbase = (c.hl * 18 + c.wl) * 32 + c.quad * 8;
  stage_cb(src, sbuf, c, 0, 0);
#pragma unroll 1
  for (int cb = 0; cb < 8; ++cb) {
    __syncthreads();                               // staged buf[cb&1] ready
    if (cb < 7) stage_cb(src, sbuf, c, (cb + 1) & 1, cb + 1);
    const _Float16* B = (const _Float16*)(sbuf + (cb & 1) * BUF_B);
    const _Float16* A = A0 + cb * (9 * 8192);
#pragma unroll
    for (int dw = 0; dw < 3; ++dw) {
      f16x8 row[6];
#pragma unroll
      for (int r = 0; r < 6; ++r)
        row[r] = *(const f16x8*)(B + rbase + (r * 18 + dw) * 32);
#pragma unroll
      for (int dh = 0; dh < 3; ++dh) {
        f16x8 af[4];
#pragma unroll
        for (int i = 0; i < 4; ++i)
          af[i] = *(const f16x8*)(A + (dh * 3 + dw) * 8192 + i * 512);
#pragma unroll
        for (int i = 0; i < 4; ++i)
#pragma unroll
          for (int j = 0; j < 4; ++j)
            acc[i][j] = __builtin_amdgcn_mfma_f32_16x16x32_f16(af[i], row[j + dh], acc[i][j], 0, 0, 0);
      }
    }
  }
  __syncthreads();                                 // sbuf free for reuse
}

// Epilogue: bias(+bias2)+relu -> f16, LDS transpose, coalesced NHWC stores.
// out_base points at (h0,w0) position; rowstride = elems per h-row (ROW*256).
__device__ __forceinline__ void epilogue_f16(const f32x4 acc[4][4],
                                             const float* __restrict__ bias,
                                             const float* __restrict__ bias2,
                                             char* smem, const TileCtx& c,
                                             _Float16* out_base, int rowstride)
{
  _Float16* lt = (_Float16*)smem;                  // [256][68]
#pragma unroll
  for (int fa = 0; fa < 4; ++fa) {
    const int co_l = fa * 16 + c.quad * 4;
    float4 bs = *(const float4*)(bias + c.co_wg + co_l);
    if (bias2) {
      const float4 b2 = *(const float4*)(bias2 + c.co_wg + co_l);
      bs.x += b2.x; bs.y += b2.y; bs.z += b2.z; bs.w += b2.w;
    }
#pragma unroll
    for (int fb = 0; fb < 4; ++fb) {
      const int n_l = (c.hl + fb) * 16 + c.wl;
      f16x4v pk;
      pk[0] = (_Float16)fmaxf(acc[fa][fb][0] + bs.x, 0.f);
      pk[1] = (_Float16)fmaxf(acc[fa][fb][1] + bs.y, 0.f);
      pk[2] = (_Float16)fmaxf(acc[fa][fb][2] + bs.z, 0.f);
      pk[3] = (_Float16)fmaxf(acc[fa][fb][3] + bs.w, 0.f);
      *(f16x4v*)&lt[n_l * 68 + co_l] = pk;
    }
  }
  __syncthreads();
  const int cc = threadIdx.x & 7, rr = threadIdx.x >> 3;
#pragma unroll
  for (int pass = 0; pass < 8; ++pass) {
    const int n_l = pass * 32 + rr;
    const int hh = n_l >> 4, ww = n_l & 15;
    uint2 q0 = *(const uint2*)&lt[n_l * 68 + cc * 8];
    uint2 q1 = *(const uint2*)&lt[n_l * 68 + cc * 8 + 4];
    *(uint4*)(out_base + (size_t)hh * rowstride + ww * 256 + c.co_wg + cc * 8) =
        make_uint4(q0.x, q0.y, q1.x, q1.y);
  }
}

// ---------------- conv kernels --------------------------------------------
// p12 as one 512-co conv: co_blk 0..7 -> set = co_blk>>2, quarter = co_blk&3
__global__ __launch_bounds__(256, 3) void k_conv_p12(
    const _Float16* __restrict__ xpad, const _Float16* __restrict__ wk,
    const float* __restrict__ bias1, const float* __restrict__ bias2,
    _Float16* __restrict__ p1, _Float16* __restrict__ p2)
{
  __shared__ __align__(16) char smem[SMEM_B];
  const int lin = blockIdx.x;
  const int co_blk = lin / 288, spatial = lin - co_blk * 288;
  const int set = co_blk >> 2, q = co_blk & 3;
  TileCtx c = make_ctx(spatial, q * 64);
  f32x4 acc[4][4];
#pragma unroll
  for (int i = 0; i < 4; ++i)
#pragma unroll
    for (int j = 0; j < 4; ++j) acc[i][j] = (f32x4){0.f, 0.f, 0.f, 0.f};
  conv_accum(xpad, wk + (size_t)set * WSET + q * (4 * 512), smem, c, acc);
  _Float16* out = (set ? p2 : p1) + ((size_t)(c.b * 96 + c.h0) * 96 + c.w0) * 256;
  epilogue_f16(acc, set ? bias2 : bias1, nullptr, smem, c, out, 96 * 256);
}

__global__ __launch_bounds__(256, 3) void k_conv_pc1(
    const _Float16* __restrict__ spad, const _Float16* __restrict__ xpad,
    const _Float16* __restrict__ wk, const float* __restrict__ bias_p,
    const float* __restrict__ bias_c1, _Float16* __restrict__ rpad)
{
  __shared__ __align__(16) char smem[SMEM_B];
  const int lin = blockIdx.x;
  const int co_blk = lin / 288, spatial = lin - co_blk * 288;
  TileCtx c = make_ctx(spatial, co_blk * 64);
  f32x4 acc[4][4];
#pragma unroll
  for (int i = 0; i < 4; ++i)
#pragma unroll
    for (int j = 0; j < 4; ++j) acc[i][j] = (f32x4){0.f, 0.f, 0.f, 0.f};
  conv_accum(spad, wk + (size_t)2 * WSET + co_blk * (4 * 512), smem, c, acc);
  conv_accum(xpad, wk + (size_t)3 * WSET + co_blk * (4 * 512), smem, c, acc);
  _Float16* out = rpad + ((size_t)(c.b * HP + c.h0 + 1) * WP + c.w0 + 1) * 256;
  epilogue_f16(acc, bias_p, bias_c1, smem, c, out, WP * 256);
}

__global__ __launch_bounds__(256, 3) void k_conv_c2(
    const _Float16* __restrict__ rpad, const _Float16* __restrict__ wk,
    const float* __restrict__ bias, float* __restrict__ dout)
{
  __shared__ __align__(16) char smem[SMEM_B];
  const int lin = blockIdx.x;
  const int co_blk = lin / 288, spatial = lin - co_blk * 288;
  TileCtx c = make_ctx(spatial, co_blk * 64);
  f32x4 acc[4][4];
#pragma unroll
  for (int i = 0; i < 4; ++i)
#pragma unroll
    for (int j = 0; j < 4; ++j) acc[i][j] = (f32x4){0.f, 0.f, 0.f, 0.f};
  conv_accum(rpad, wk + (size_t)4 * WSET + co_blk * (4 * 512), smem, c, acc);
  // NCHW f32 stores: lanes (wl) = consecutive w
#pragma unroll
  for (int fb = 0; fb < 4; ++fb) {
    const int h = c.h0 + c.hl + fb;
    const int w = c.w0 + c.wl;
    float* op = dout + (size_t)c.b * 2359296 + h * 96 + w;
#pragma unroll
    for (int fa = 0; fa < 4; ++fa) {
      const int co = c.co_wg + fa * 16 + c.quad * 4;
      const float4 bs = *(const float4*)(bias + co);
      op[(size_t)(co + 0) * 9216] = fmaxf(acc[fa][fb][0] + bs.x, 0.f);
      op[(size_t)(co + 1) * 9216] = fmaxf(acc[fa][fb][1] + bs.y, 0.f);
      op[(size_t)(co + 2) * 9216] = fmaxf(acc[fa][fb][2] + bs.z, 0.f);
      op[(size_t)(co + 3) * 9216] = fmaxf(acc[fa][fb][3] + bs.w, 0.f);
    }
  }
}

// ---------------- aux kernels ---------------------------------------------
__global__ void k_pack_x(const float* __restrict__ x, _Float16* __restrict__ xpad)
{
  __shared__ float tile[32][33];
  const int bh = blockIdx.x;
  const int b = bh / 96, h = bh - b * 96;
  const int c0 = blockIdx.y * 32, w0 = blockIdx.z * 32;
  const int tx = threadIdx.x & 31, ty = threadIdx.x >> 5;
#pragma unroll
  for (int i = 0; i < 4; ++i) {
    int cI = c0 + ty + i * 8;
    tile[ty + i * 8][tx] = x[(((size_t)b * 256 + cI) * 96 + h) * 96 + w0 + tx];
  }
  __syncthreads();
#pragma unroll
  for (int i = 0; i < 4; ++i) {
    int w = w0 + ty + i * 8;
    xpad[((size_t)(b * HP + h + 1) * WP + (w + 1)) * 256 + c0 + tx] =
        (_Float16)tile[tx][ty + i * 8];
  }
}

// repack into tiled layout: idx = ((cb*9+tap)*16 + cog)*512 + m*32 + kk
__global__ void k_repack_w(const float* w0, const float* g0, const float* w1, const float* g1,
                           const float* w2, const float* g2, const float* w3, const float* g3,
                           const float* w4, const float* g4, _Float16* __restrict__ wk)
{
  const int set = blockIdx.y;
  const float* w; const float* g;
  switch (set) {
    case 0: w = w0; g = g0; break;
    case 1: w = w1; g = g1; break;
    case 2: w = w2; g = g2; break;
    case 3: w = w3; g = g3; break;
    default: w = w4; g = g4; break;
  }
  const int t = blockIdx.x * 256 + threadIdx.x;   // co*256 + ci
  const int co = t >> 8, ci = t & 255;
  const int cb = ci >> 5, kk = ci & 31, cog = co >> 4, m = co & 15;
  const float gv = g[co];
  const float* src = w + ((size_t)co * 256 + ci) * 9;
  _Float16* dst = wk + (size_t)set * WSET + cog * 512 + m * 32 + kk;
#pragma unroll
  for (int tap = 0; tap < 9; ++tap)
    dst[(cb * 9 + tap) * 8192] = (_Float16)(src[tap] * gv);
}

__global__ void k_reduce_h(const _Float16* __restrict__ p1, float* __restrict__ u)
{
  const int t = blockIdx.x * 256 + threadIdx.x;
  const int c = t & 255; const int bw = t >> 8;
  const int b = bw / 96, w = bw - b * 96;
  const _Float16* p = p1 + ((size_t)b * 9216 + w) * 256 + c;
  float m = 0.f;
#pragma unroll 4
  for (int h = 0; h < 96; ++h) m = fmaxf(m, (float)p[(size_t)h * 24576]);
  u[t] = m;
}

__global__ void k_reduce_w(const _Float16* __restrict__ p2, float* __restrict__ v)
{
  const int t = blockIdx.x * 256 + threadIdx.x;
  const int c = t & 255; const int bh = t >> 8;
  const _Float16* p = p2 + (size_t)bh * 96 * 256 + c;
  float m = 0.f;
#pragma unroll 4
  for (int w = 0; w < 96; ++w) m = fmaxf(m, (float)p[w * 256]);
  v[t] = m;
}

__global__ void k_build_s(const float* __restrict__ u, const float* __restrict__ v,
                          _Float16* __restrict__ spad)
{
  const int bhw = blockIdx.x;
  const int c = threadIdx.x;
  const int b = bhw / 9216; int r = bhw - b * 9216;
  const int h = r / 96, w = r - h * 96;
  float s = u[((size_t)b * 96 + w) * 256 + c] + v[((size_t)b * 96 + h) * 256 + c];
  spad[((size_t)(b * HP + h + 1) * WP + (w + 1)) * 256 + c] = (_Float16)s;
}

// ---------------- launcher -------------------------------------------------
extern "C" void kernel_launch(void* const* d_in, const int* in_sizes, int n_in,
                              void* d_out, int out_size, void* d_ws, size_t ws_size,
                              hipStream_t stream)
{
  const float* x    = (const float*)d_in[0];
  const float* w_p1 = (const float*)d_in[1];
  const float* g_p1 = (const float*)d_in[2];
  const float* b_p1 = (const float*)d_in[3];
  const float* w_p2 = (const float*)d_in[4];
  const float* g_p2 = (const float*)d_in[5];
  const float* b_p2 = (const float*)d_in[6];
  const float* w_p  = (const float*)d_in[7];
  const float* g_p  = (const float*)d_in[8];
  const float* b_p  = (const float*)d_in[9];
  const float* w_c1 = (const float*)d_in[10];
  const float* g_c1 = (const float*)d_in[11];
  const float* b_c1 = (const float*)d_in[12];
  const float* w_c2 = (const float*)d_in[13];
  const float* g_c2 = (const float*)d_in[14];
  const float* b_c2 = (const float*)d_in[15];

  char* ws = (char*)d_ws;
  size_t off = 0;
  _Float16* x_pad = (_Float16*)(ws + off); off += XPAD_E * 2;
  _Float16* s_pad = (_Float16*)(ws + off); off += XPAD_E * 2;
  _Float16* r_pad = (_Float16*)(ws + off); off += XPAD_E * 2;
  _Float16* wks   = (_Float16*)(ws + off); off += (size_t)5 * WSET * 2;
  _Float16* p1buf = (_Float16*)(ws + off); off += PBUF_E * 2;
  _Float16* p2buf = (_Float16*)(ws + off); off += PBUF_E * 2;
  float*    u     = (float*)(ws + off);    off += (size_t)UV_E * 4;
  float*    v     = (float*)(ws + off);    off += (size_t)UV_E * 4;
  (void)ws_size; (void)in_sizes; (void)n_in; (void)out_size;

  hipMemsetAsync(x_pad, 0, XPAD_E * 2, stream);
  hipMemsetAsync(s_pad, 0, XPAD_E * 2, stream);
  hipMemsetAsync(r_pad, 0, XPAD_E * 2, stream);

  k_pack_x  <<<dim3(768, 8, 3), 256, 0, stream>>>(x, x_pad);
  k_repack_w<<<dim3(256, 5),    256, 0, stream>>>(w_p1, g_p1, w_p2, g_p2, w_p, g_p,
                                                  w_c1, g_c1, w_c2, g_c2, wks);
  k_conv_p12<<<2304, 256, 0, stream>>>(x_pad, wks, b_p1, b_p2, p1buf, p2buf);
  k_reduce_h<<<768, 256, 0, stream>>>(p1buf, u);
  k_reduce_w<<<768, 256, 0, stream>>>(p2buf, v);
  k_build_s <<<dim3(73728), 256, 0, stream>>>(u, v, s_pad);
  k_conv_pc1<<<1152, 256, 0, stream>>>(s_pad, x_pad, wks, b_p, b_c1, r_pad);
  k_conv_c2 <<<1152, 256, 0, stream>>>(r_pad, wks, b_c2, (float*)d_out);
}

// Round 5
// 646.654 us; speedup vs baseline: 1.1432x; 1.1432x over previous
//
#include <hip/hip_runtime.h>

// ct_layer round 5: algebraic fusion.
//   pool identity: rev-cummax then cummax = broadcast max  ->  s = u[w]+v[h].
//   conv_p separability: conv_p(s)[co,h,w] = U'[hcase][co,w] + V'[wcase][co,h]
//     where U' = 1D conv of u with dh-summed weights (3 h-edge cases),
//           V' = 1D conv of v with dw-summed weights (3 w-edge cases).
//   p12: conv -> bias+relu -> in-block h/w max -> atomicMax into u/v
//     (uint-compare trick on non-negative floats; p1/p2 never materialized).
// Pipeline: pack_x, repack_w, repack_uvw | p12 -> uv1d -> c1f -> c2.

typedef _Float16 f16x8 __attribute__((ext_vector_type(8)));
typedef _Float16 f16x4v __attribute__((ext_vector_type(4)));
typedef float f32x4 __attribute__((ext_vector_type(4)));

#define HP 98
#define WP 98
#define KTOT 2304
#define WSET (256*KTOT)                // 589824 elems per weight set
#define XPAD_E ((size_t)8*HP*WP*256)
#define UVP_E  ((size_t)8*98*256)      // u_pad/v_pad f32 (atomic targets, padded)
#define UV2_E  ((size_t)3*8*96*256)    // u2/v2 f32 [case][b][pos][co]
#define WUV_SET 196608                 // 256co * 768k per (t,case)

#define BUF_B 24576            // one staged ci-slice: 384 pos * 64B (324 valid)
#define SMEM_B 49152           // 2*BUF_B; epilogue lt needs 256*68*2=34816

struct TileCtx {
  unsigned goff[6];
  unsigned lds_stage;
  unsigned aoff;
  int hl, wl, quad;
  int co_wg;
  int b, h0, w0;
};

__device__ __forceinline__ TileCtx make_ctx(int spatial, int co_wg)
{
  TileCtx c;
  c.co_wg = co_wg;
  c.b = spatial / 36;
  const int tt = spatial - c.b * 36;
  const int ht = tt / 6, wt = tt - ht * 6;
  c.h0 = ht * 16; c.w0 = wt * 16;
  const int tid = threadIdx.x, lane = tid & 63, wv = tid >> 6;
  c.quad = lane >> 4; c.wl = lane & 15;
  c.hl = wv * 4;
  c.aoff = (unsigned)(c.wl * 32 + c.quad * 8);
  const unsigned base_hw = (unsigned)(c.b * HP + c.h0) * WP + c.w0;
#pragma unroll
  for (int t = 0; t < 6; ++t) {
    int pos = (wv * 6 + t) * 16 + (lane >> 2);   // 0..383; 324..383 dummy
    if (pos > 323) pos = 323;
    const int wh = pos / 18, ww = pos - wh * 18;
    c.goff[t] = (base_hw + (unsigned)(wh * WP + ww)) * 256u + (lane & 3) * 8u;
  }
  c.lds_stage = (unsigned)(wv * 6) * 1024u + (unsigned)lane * 16u;
  return c;
}

__device__ __forceinline__ void stage_cb(const _Float16* __restrict__ src,
                                         char* sbuf, const TileCtx& c,
                                         int buf, int cb)
{
  char* l0 = sbuf + buf * BUF_B + c.lds_stage;
#pragma unroll
  for (int t = 0; t < 6; ++t) {
    const _Float16* g = src + c.goff[t] + cb * 32;
    __builtin_amdgcn_global_load_lds(
        (const __attribute__((address_space(1))) void*)g,
        (__attribute__((address_space(3))) void*)(l0 + t * 1024), 16, 0, 0);
  }
}

// Full conv accumulation (K = 9 taps x 256 ci) into acc[4][4].
// wkb points at this block's 64-co slice; tile idx = (cb*9+tap)*8192 + cog*512 + m*32 + kk
__device__ __forceinline__ void conv_accum(const _Float16* __restrict__ src,
                                           const _Float16* __restrict__ wkb,
                                           char* sbuf, const TileCtx& c,
                                           f32x4 acc[4][4])
{
  const _Float16* A0 = wkb + c.aoff;
  const int rbase = (c.hl * 18 + c.wl) * 32 + c.quad * 8;
  stage_cb(src, sbuf, c, 0, 0);
#pragma unroll 1
  for (int cb = 0; cb < 8; ++cb) {
    __syncthreads();
    if (cb < 7) stage_cb(src, sbuf, c, (cb + 1) & 1, cb + 1);
    const _Float16* B = (const _Float16*)(sbuf + (cb & 1) * BUF_B);
    const _Float16* A = A0 + cb * (9 * 8192);
#pragma unroll
    for (int dw = 0; dw < 3; ++dw) {
      f16x8 row[6];
#pragma unroll
      for (int r = 0; r < 6; ++r)
        row[r] = *(const f16x8*)(B + rbase + (r * 18 + dw) * 32);
#pragma unroll
      for (int dh = 0; dh < 3; ++dh) {
        f16x8 af[4];
#pragma unroll
        for (int i = 0; i < 4; ++i)
          af[i] = *(const f16x8*)(A + (dh * 3 + dw) * 8192 + i * 512);
#pragma unroll
        for (int i = 0; i < 4; ++i)
#pragma unroll
          for (int j = 0; j < 4; ++j)
            acc[i][j] = __builtin_amdgcn_mfma_f32_16x16x32_f16(af[i], row[j + dh], acc[i][j], 0, 0, 0);
      }
    }
  }
  __syncthreads();
}

// ---------------- conv kernel: p1/p2 branches, fused max-pool epilogue ----
// 512-co conv: co_blk 0..7 -> set = co_blk>>2 (p1/p2), quarter = co_blk&3.
// Epilogue: bias+relu -> lt[n][co] -> max over h (set0) / w (set1) -> atomicMax.
__global__ __launch_bounds__(256, 3) void k_conv_p12(
    const _Float16* __restrict__ xpad, const _Float16* __restrict__ wk,
    const float* __restrict__ bias1, const float* __restrict__ bias2,
    float* __restrict__ u_pad, float* __restrict__ v_pad)
{
  __shared__ __align__(16) char smem[SMEM_B];
  const int lin = blockIdx.x;
  const int co_blk = lin / 288, spatial = lin - co_blk * 288;
  const int set = co_blk >> 2, q = co_blk & 3;
  TileCtx c = make_ctx(spatial, q * 64);
  f32x4 acc[4][4];
#pragma unroll
  for (int i = 0; i < 4; ++i)
#pragma unroll
    for (int j = 0; j < 4; ++j) acc[i][j] = (f32x4){0.f, 0.f, 0.f, 0.f};
  conv_accum(xpad, wk + (size_t)set * WSET + q * (4 * 512), smem, c, acc);

  const float* bias = set ? bias2 : bias1;
  _Float16* lt = (_Float16*)smem;                  // [256][68]
#pragma unroll
  for (int fa = 0; fa < 4; ++fa) {
    const int co_l = fa * 16 + c.quad * 4;
    const float4 bs = *(const float4*)(bias + c.co_wg + co_l);
#pragma unroll
    for (int fb = 0; fb < 4; ++fb) {
      const int n_l = (c.hl + fb) * 16 + c.wl;
      f16x4v pk;
      pk[0] = (_Float16)fmaxf(acc[fa][fb][0] + bs.x, 0.f);
      pk[1] = (_Float16)fmaxf(acc[fa][fb][1] + bs.y, 0.f);
      pk[2] = (_Float16)fmaxf(acc[fa][fb][2] + bs.z, 0.f);
      pk[3] = (_Float16)fmaxf(acc[fa][fb][3] + bs.w, 0.f);
      *(f16x4v*)&lt[n_l * 68 + co_l] = pk;
    }
  }
  __syncthreads();
  // 1024 (pos, co) pairs, 4 per thread; max over the other spatial dim.
#pragma unroll
  for (int r = 0; r < 4; ++r) {
    const int idx = threadIdx.x * 4 + r;
    const int co_l = idx & 63, sp = idx >> 6;      // sp: w_local (set0) / h_local (set1)
    float m = 0.f;
#pragma unroll
    for (int qq = 0; qq < 16; ++qq) {
      const int n_l = set == 0 ? (qq * 16 + sp) : (sp * 16 + qq);
      m = fmaxf(m, (float)lt[n_l * 68 + co_l]);
    }
    float* tgt = set == 0
        ? &u_pad[((size_t)c.b * 98 + (c.w0 + sp + 1)) * 256 + c.co_wg + co_l]
        : &v_pad[((size_t)c.b * 98 + (c.h0 + sp + 1)) * 256 + c.co_wg + co_l];
    atomicMax((unsigned int*)tgt, __float_as_uint(m));   // values >= 0: exact
  }
}

// ---------------- 1D convs of u,v with case-summed weights (mini GEMM) ----
// grid = t(2) x case(3) x b(8) = 48 blocks. Block: M=256co x N=96pos, K=768.
// out: u2/v2[(case*8+b)*96+pos)*256+co] = raw linear conv (no bias).
__global__ __launch_bounds__(256, 2) void k_uv1d(
    const float* __restrict__ u_pad, const float* __restrict__ v_pad,
    const _Float16* __restrict__ wuv, float* __restrict__ u2,
    float* __restrict__ v2)
{
  const int id = blockIdx.x;
  const int b = id & 7, cs = (id >> 3) % 3, t = id / 24;
  const float* src = t ? v_pad : u_pad;
  float* dst = t ? v2 : u2;
  const _Float16* A0 = wuv + (size_t)(t * 3 + cs) * WUV_SET;
  const int lane = threadIdx.x & 63, wv = threadIdx.x >> 6;
  const int quad = lane >> 4, l16 = lane & 15;

  f32x4 acc[4][6];
#pragma unroll
  for (int i = 0; i < 4; ++i)
#pragma unroll
    for (int j = 0; j < 6; ++j) acc[i][j] = (f32x4){0.f, 0.f, 0.f, 0.f};

#pragma unroll 1
  for (int kb = 0; kb < 24; ++kb) {
    const int dw = kb >> 3, cb = kb & 7;
    f16x8 bf[6];
#pragma unroll
    for (int j = 0; j < 6; ++j) {
      const int pos = j * 16 + l16;
      const float* p = src + ((size_t)b * 98 + (pos + dw)) * 256 + cb * 32 + quad * 8;
      const float4 x0 = *(const float4*)p;
      const float4 x1 = *(const float4*)(p + 4);
      f16x8 v;
      v[0] = (_Float16)x0.x; v[1] = (_Float16)x0.y; v[2] = (_Float16)x0.z; v[3] = (_Float16)x0.w;
      v[4] = (_Float16)x1.x; v[5] = (_Float16)x1.y; v[6] = (_Float16)x1.z; v[7] = (_Float16)x1.w;
      bf[j] = v;
    }
    f16x8 af[4];
#pragma unroll
    for (int i = 0; i < 4; ++i)
      af[i] = *(const f16x8*)(A0 + (size_t)(kb * 16 + wv * 4 + i) * 512 + l16 * 32 + quad * 8);
#pragma unroll
    for (int i = 0; i < 4; ++i)
#pragma unroll
      for (int j = 0; j < 6; ++j)
        acc[i][j] = __builtin_amdgcn_mfma_f32_16x16x32_f16(af[i], bf[j], acc[i][j], 0, 0, 0);
  }
#pragma unroll
  for (int i = 0; i < 4; ++i)
#pragma unroll
    for (int j = 0; j < 6; ++j) {
      const int pos = j * 16 + l16;
      const int co = wv * 64 + i * 16 + quad * 4;
      *(f32x4*)(dst + ((size_t)(cs * 8 + b) * 96 + pos) * 256 + co) = acc[i][j];
    }
}

// ---------------- conv_c1 + U' + V' + biases, relu -> r_pad NHWC f16 ------
__global__ __launch_bounds__(256, 3) void k_conv_c1f(
    const _Float16* __restrict__ xpad, const _Float16* __restrict__ wkc1,
    const float* __restrict__ bias_p, const float* __restrict__ bias_c1,
    const float* __restrict__ u2, const float* __restrict__ v2,
    _Float16* __restrict__ rpad)
{
  __shared__ __align__(16) char smem[SMEM_B];
  const int lin = blockIdx.x;
  const int co_blk = lin / 288, spatial = lin - co_blk * 288;
  TileCtx c = make_ctx(spatial, co_blk * 64);
  f32x4 acc[4][4];
#pragma unroll
  for (int i = 0; i < 4; ++i)
#pragma unroll
    for (int j = 0; j < 4; ++j) acc[i][j] = (f32x4){0.f, 0.f, 0.f, 0.f};
  conv_accum(xpad, wkc1 + co_blk * (4 * 512), smem, c, acc);

  const int w = c.w0 + c.wl;
  const int wcase = (w == 0) ? 0 : ((w == 95) ? 2 : 1);
  _Float16* lt = (_Float16*)smem;
#pragma unroll
  for (int fa = 0; fa < 4; ++fa) {
    const int co_l = fa * 16 + c.quad * 4;
    float4 bs = *(const float4*)(bias_p + c.co_wg + co_l);
    const float4 b2 = *(const float4*)(bias_c1 + c.co_wg + co_l);
    bs.x += b2.x; bs.y += b2.y; bs.z += b2.z; bs.w += b2.w;
#pragma unroll
    for (int fb = 0; fb < 4; ++fb) {
      const int h = c.h0 + c.hl + fb;
      const int hcase = (h == 0) ? 0 : ((h == 95) ? 2 : 1);
      const float4 uq = *(const float4*)(u2 + ((size_t)(hcase * 8 + c.b) * 96 + w) * 256 + c.co_wg + co_l);
      const float4 vq = *(const float4*)(v2 + ((size_t)(wcase * 8 + c.b) * 96 + h) * 256 + c.co_wg + co_l);
      const int n_l = (c.hl + fb) * 16 + c.wl;
      f16x4v pk;
      pk[0] = (_Float16)fmaxf(acc[fa][fb][0] + bs.x + uq.x + vq.x, 0.f);
      pk[1] = (_Float16)fmaxf(acc[fa][fb][1] + bs.y + uq.y + vq.y, 0.f);
      pk[2] = (_Float16)fmaxf(acc[fa][fb][2] + bs.z + uq.z + vq.z, 0.f);
      pk[3] = (_Float16)fmaxf(acc[fa][fb][3] + bs.w + uq.w + vq.w, 0.f);
      *(f16x4v*)&lt[n_l * 68 + co_l] = pk;
    }
  }
  __syncthreads();
  _Float16* out_base = rpad + ((size_t)(c.b * HP + c.h0 + 1) * WP + c.w0 + 1) * 256;
  const int cc = threadIdx.x & 7, rr = threadIdx.x >> 3;
#pragma unroll
  for (int pass = 0; pass < 8; ++pass) {
    const int n_l = pass * 32 + rr;
    const int hh = n_l >> 4, ww = n_l & 15;
    uint2 q0 = *(const uint2*)&lt[n_l * 68 + cc * 8];
    uint2 q1 = *(const uint2*)&lt[n_l * 68 + cc * 8 + 4];
    *(uint4*)(out_base + (size_t)hh * (WP * 256) + ww * 256 + c.co_wg + cc * 8) =
        make_uint4(q0.x, q0.y, q1.x, q1.y);
  }
}

// ---------------- final conv, relu, NCHW f32 to d_out ---------------------
__global__ __launch_bounds__(256, 3) void k_conv_c2(
    const _Float16* __restrict__ rpad, const _Float16* __restrict__ wkc2,
    const float* __restrict__ bias, float* __restrict__ dout)
{
  __shared__ __align__(16) char smem[SMEM_B];
  const int lin = blockIdx.x;
  const int co_blk = lin / 288, spatial = lin - co_blk * 288;
  TileCtx c = make_ctx(spatial, co_blk * 64);
  f32x4 acc[4][4];
#pragma unroll
  for (int i = 0; i < 4; ++i)
#pragma unroll
    for (int j = 0; j < 4; ++j) acc[i][j] = (f32x4){0.f, 0.f, 0.f, 0.f};
  conv_accum(rpad, wkc2 + co_blk * (4 * 512), smem, c, acc);
#pragma unroll
  for (int fb = 0; fb < 4; ++fb) {
    const int h = c.h0 + c.hl + fb;
    const int w = c.w0 + c.wl;
    float* op = dout + (size_t)c.b * 2359296 + h * 96 + w;
#pragma unroll
    for (int fa = 0; fa < 4; ++fa) {
      const int co = c.co_wg + fa * 16 + c.quad * 4;
      const float4 bs = *(const float4*)(bias + co);
      op[(size_t)(co + 0) * 9216] = fmaxf(acc[fa][fb][0] + bs.x, 0.f);
      op[(size_t)(co + 1) * 9216] = fmaxf(acc[fa][fb][1] + bs.y, 0.f);
      op[(size_t)(co + 2) * 9216] = fmaxf(acc[fa][fb][2] + bs.z, 0.f);
      op[(size_t)(co + 3) * 9216] = fmaxf(acc[fa][fb][3] + bs.w, 0.f);
    }
  }
}

// ---------------- aux kernels ---------------------------------------------
__global__ void k_pack_x(const float* __restrict__ x, _Float16* __restrict__ xpad)
{
  __shared__ float tile[32][33];
  const int bh = blockIdx.x;
  const int b = bh / 96, h = bh - b * 96;
  const int c0 = blockIdx.y * 32, w0 = blockIdx.z * 32;
  const int tx = threadIdx.x & 31, ty = threadIdx.x >> 5;
#pragma unroll
  for (int i = 0; i < 4; ++i) {
    int cI = c0 + ty + i * 8;
    tile[ty + i * 8][tx] = x[(((size_t)b * 256 + cI) * 96 + h) * 96 + w0 + tx];
  }
  __syncthreads();
#pragma unroll
  for (int i = 0; i < 4; ++i) {
    int w = w0 + ty + i * 8;
    xpad[((size_t)(b * HP + h + 1) * WP + (w + 1)) * 256 + c0 + tx] =
        (_Float16)tile[tx][ty + i * 8];
  }
}

// main conv weights -> tiled layout: idx = ((cb*9+tap)*16 + cog)*512 + m*32 + kk
__global__ void k_repack_w(const float* w0, const float* g0, const float* w1, const float* g1,
                           const float* w2, const float* g2, const float* w3, const float* g3,
                           const float* w4, const float* g4, _Float16* __restrict__ wk)
{
  const int set = blockIdx.y;
  const float* w; const float* g;
  switch (set) {
    case 0: w = w0; g = g0; break;
    case 1: w = w1; g = g1; break;
    case 2: w = w2; g = g2; break;
    case 3: w = w3; g = g3; break;
    default: w = w4; g = g4; break;
  }
  const int t = blockIdx.x * 256 + threadIdx.x;   // co*256 + ci
  const int co = t >> 8, ci = t & 255;
  const int cb = ci >> 5, kk = ci & 31, cog = co >> 4, m = co & 15;
  const float gv = g[co];
  const float* src = w + ((size_t)co * 256 + ci) * 9;
  _Float16* dst = wk + (size_t)set * WSET + cog * 512 + m * 32 + kk;
#pragma unroll
  for (int tap = 0; tap < 9; ++tap)
    dst[(cb * 9 + tap) * 8192] = (_Float16)(src[tap] * gv);
}

// case-summed 1D weights for U'/V': wuv[(t*3+cs)] tile layout
//   k = dsum_axis_tap*256 + ci ; idx = (kb*16+cog)*512 + m*32 + kk
__global__ void k_repack_uvw(const float* __restrict__ wp, const float* __restrict__ gp,
                             _Float16* __restrict__ wuv)
{
  const int t = blockIdx.y >> 1 ? 1 : (blockIdx.y / 3);   // handled below
  const int tcs = blockIdx.y;                             // 0..5 = t*3+cs
  const int tt = tcs / 3, cs = tcs - tt * 3;
  const int idx = blockIdx.x * 256 + threadIdx.x;         // co*256 + ci
  const int co = idx >> 8, ci = idx & 255;
  const float gv = gp[co];
  const float* src = wp + ((size_t)co * 256 + ci) * 9;    // [dh][dw]
  const int lo = (cs == 0) ? 1 : 0, hi = (cs == 2) ? 1 : 2;
  _Float16* base = wuv + (size_t)tcs * WUV_SET;
  (void)t;
#pragma unroll
  for (int d = 0; d < 3; ++d) {                           // kept tap index
    float s = 0.f;
    for (int e = lo; e <= hi; ++e)                        // summed-out axis
      s += (tt == 0) ? src[e * 3 + d]                     // t=0: sum dh, keep dw
                     : src[d * 3 + e];                    // t=1: sum dw, keep dh
    const int k = d * 256 + ci;
    const int kb = k >> 5, kk = k & 31;
    base[(size_t)(kb * 16 + (co >> 4)) * 512 + (co & 15) * 32 + kk] = (_Float16)(s * gv);
  }
}

// ---------------- launcher -------------------------------------------------
extern "C" void kernel_launch(void* const* d_in, const int* in_sizes, int n_in,
                              void* d_out, int out_size, void* d_ws, size_t ws_size,
                              hipStream_t stream)
{
  const float* x    = (const float*)d_in[0];
  const float* w_p1 = (const float*)d_in[1];
  const float* g_p1 = (const float*)d_in[2];
  const float* b_p1 = (const float*)d_in[3];
  const float* w_p2 = (const float*)d_in[4];
  const float* g_p2 = (const float*)d_in[5];
  const float* b_p2 = (const float*)d_in[6];
  const float* w_p  = (const float*)d_in[7];
  const float* g_p  = (const float*)d_in[8];
  const float* b_p  = (const float*)d_in[9];
  const float* w_c1 = (const float*)d_in[10];
  const float* g_c1 = (const float*)d_in[11];
  const float* b_c1 = (const float*)d_in[12];
  const float* w_c2 = (const float*)d_in[13];
  const float* g_c2 = (const float*)d_in[14];
  const float* b_c2 = (const float*)d_in[15];

  char* ws = (char*)d_ws;
  size_t off = 0;
  _Float16* x_pad = (_Float16*)(ws + off); off += XPAD_E * 2;
  _Float16* r_pad = (_Float16*)(ws + off); off += XPAD_E * 2;
  _Float16* wks   = (_Float16*)(ws + off); off += (size_t)5 * WSET * 2;
  _Float16* wuv   = (_Float16*)(ws + off); off += (size_t)6 * WUV_SET * 2;
  float*    u_pad = (float*)(ws + off);    off += UVP_E * 4;
  float*    v_pad = (float*)(ws + off);    off += UVP_E * 4;
  float*    u2    = (float*)(ws + off);    off += UV2_E * 4;
  float*    v2    = (float*)(ws + off);    off += UV2_E * 4;
  (void)ws_size; (void)in_sizes; (void)n_in; (void)out_size;

  hipMemsetAsync(x_pad, 0, XPAD_E * 2, stream);
  hipMemsetAsync(r_pad, 0, XPAD_E * 2, stream);
  hipMemsetAsync(u_pad, 0, UVP_E * 4, stream);     // atomic targets + zero pad
  hipMemsetAsync(v_pad, 0, UVP_E * 4, stream);

  k_pack_x    <<<dim3(768, 8, 3), 256, 0, stream>>>(x, x_pad);
  k_repack_w  <<<dim3(256, 5),    256, 0, stream>>>(w_p1, g_p1, w_p2, g_p2, w_p, g_p,
                                                    w_c1, g_c1, w_c2, g_c2, wks);
  k_repack_uvw<<<dim3(256, 6),    256, 0, stream>>>(w_p, g_p, wuv);
  k_conv_p12  <<<2304, 256, 0, stream>>>(x_pad, wks, b_p1, b_p2, u_pad, v_pad);
  k_uv1d      <<<48,   256, 0, stream>>>(u_pad, v_pad, wuv, u2, v2);
  k_conv_c1f  <<<1152, 256, 0, stream>>>(x_pad, wks + (size_t)3 * WSET, b_p, b_c1,
                                         u2, v2, r_pad);
  k_conv_c2   <<<1152, 256, 0, stream>>>(r_pad, wks + (size_t)4 * WSET, b_c2,
                                         (float*)d_out);
}